// Round 6
// baseline (1794.848 us; speedup 1.0000x reference)
//
#include <hip/hip_runtime.h>
#include <math.h>

#define Bg 32
#define Ng 2048
#define Kn 20
#define BNn (Bg*Ng)
#define En (BNn*Kn)
#define Hd 64
#define Cd 40

// knn-mfma params
#define KK 24            // approx top-K kept per j-quarter (96 cands/row)
#define CAPB 7

typedef __attribute__((ext_vector_type(8))) short bf16x8;
typedef __attribute__((ext_vector_type(4))) float f32x4;

__device__ __forceinline__ unsigned enc_f32(float f){
  unsigned u = __float_as_uint(f);
  return ((int)u < 0) ? ~u : (u | 0x80000000u);
}

// ---------- weight prep
__global__ void prep_w_kernel(const float* __restrict__ w1c, const float* __restrict__ w1d1,
                              const float* __restrict__ w1d2,
                              float* __restrict__ wpq0, float* __restrict__ wpq1,
                              float* __restrict__ wpq2){
  int t = blockIdx.x*256 + threadIdx.x;
  if (t < 3*128){
    int d = t >> 7, l = t & 127;
    wpq0[t] = (l < 64) ? (w1c[d*64 + l] - w1c[(d+3)*64 + l]) : w1c[(d+3)*64 + (l-64)];
  }
  if (t < 64*128){
    int d = t >> 7, l = t & 127;
    wpq1[t] = (l < 64) ? (w1d1[d*64 + l] - w1d1[(d+64)*64 + l]) : w1d1[(d+64)*64 + (l-64)];
    wpq2[t] = (l < 64) ? (w1d2[d*64 + l] - w1d2[(d+64)*64 + l]) : w1d2[(d+64)*64 + (l-64)];
  }
}

__global__ void zero_kernel(int* __restrict__ p){
  p[blockIdx.x*256 + threadIdx.x] = 0;
}

__global__ void init_enc_kernel(unsigned int* __restrict__ enc){
  enc[blockIdx.x*256 + threadIdx.x] = 0x007FFFFFu;   // enc(-inf)
}

// ---------- X[BN,D] @ wpq[D,128] -> P,Q
template<int D>
__global__ __launch_bounds__(128) void gemm_pq_kernel(const float* __restrict__ x,
                               const float* __restrict__ w,
                               float* __restrict__ P, float* __restrict__ Q){
  __shared__ float xs[8*D];
  int l = threadIdx.x;
  int node0 = blockIdx.x*8;
  float wc[D];
  #pragma unroll
  for (int d=0; d<D; d++) wc[d] = w[d*128 + l];
  for (int i=l; i < 8*D; i += 128) xs[i] = x[(size_t)node0*D + i];
  __syncthreads();
  #pragma unroll
  for (int n=0; n<8; n++){
    float s = 0.f;
    #pragma unroll
    for (int d=0; d<D; d++) s = fmaf(xs[n*D+d], wc[d], s);
    int node = node0 + n;
    if (l < 64) P[(size_t)node*64 + l] = s;
    else        Q[(size_t)node*64 + (l-64)] = s;
  }
}

// ---------- sq norms + bf16 copy of X (first static layer input path)
__global__ __launch_bounds__(256) void sqxb_kernel(const float* __restrict__ x,
        float* __restrict__ sq, unsigned short* __restrict__ xb){
  int t = blockIdx.x*256 + threadIdx.x;
  int node = t >> 6, l = t & 63;
  float v = x[t];
  unsigned u = __float_as_uint(v);
  xb[t] = (unsigned short)((u + 0x7FFFu + ((u >> 16) & 1u)) >> 16);  // RNE fp32->bf16
  float s = v*v;
  #pragma unroll
  for (int o=32; o; o>>=1) s += __shfl_xor(s, o, 64);
  if (l == 0) sq[node] = s;
}

// ---------- fused decode(+b2,+ELU) -> X, bf16 XB, SQ
__global__ __launch_bounds__(256) void decode_sqxb_kernel(const unsigned int* __restrict__ enc,
        const float* __restrict__ b2, float* __restrict__ x,
        float* __restrict__ sq, unsigned short* __restrict__ xb){
  int t = blockIdx.x*256 + threadIdx.x;
  int node = t >> 6, l = t & 63;
  unsigned int e = enc[t];
  unsigned int bits = (e & 0x80000000u) ? (e ^ 0x80000000u) : ~e;
  float f = __uint_as_float(bits);
  if (isfinite(f)) f += b2[l]; else f = 0.f;
  f = f > 0.f ? f : expm1f(f);
  x[t] = f;
  unsigned u = __float_as_uint(f);
  xb[t] = (unsigned short)((u + 0x7FFFu + ((u >> 16) & 1u)) >> 16);
  float s = f*f;
  #pragma unroll
  for (int o=32; o; o>>=1) s += __shfl_xor(s, o, 64);
  if (l == 0) sq[node] = s;
}

// ---------- CSR build
__global__ void count_kernel(const int* __restrict__ ei, int* __restrict__ deg){
  int e = blockIdx.x*256 + threadIdx.x;
  atomicAdd(&deg[ei[En + e]], 1);
}

__global__ __launch_bounds__(1024) void scan_kernel(const int* __restrict__ deg,
        int* __restrict__ rowptr, int* __restrict__ cursor){
  __shared__ int ps[1024];
  int t = threadIdx.x;
  int base = t*64;
  int s = 0;
  for (int k=0;k<64;k++) s += deg[base+k];
  ps[t] = s; __syncthreads();
  for (int off=1; off<1024; off<<=1){
    int v = (t>=off) ? ps[t-off] : 0;
    __syncthreads();
    ps[t] += v;
    __syncthreads();
  }
  int run = (t>0) ? ps[t-1] : 0;
  for (int k=0;k<64;k++){
    rowptr[base+k] = run; cursor[base+k] = run;
    run += deg[base+k];
  }
  if (t==1023) rowptr[BNn] = run;
}

__global__ void scatter_kernel(const int* __restrict__ ei, int* __restrict__ cursor,
                               int* __restrict__ csrc, int* __restrict__ enid){
  int e = blockIdx.x*256 + threadIdx.x;
  int s = ei[e], d = ei[En + e];
  int pos = atomicAdd(&cursor[d], 1);
  csrc[pos] = s;
  enid[pos] = d;
}

// ---------- static EdgeConv as edge-batched GEMM + LDS-reduced node-max epilogue
#define FMA8(av, r) \
  acc[r][0]=fmaf(av,b0.x,acc[r][0]); acc[r][1]=fmaf(av,b0.y,acc[r][1]); \
  acc[r][2]=fmaf(av,b0.z,acc[r][2]); acc[r][3]=fmaf(av,b0.w,acc[r][3]); \
  acc[r][4]=fmaf(av,b1v.x,acc[r][4]); acc[r][5]=fmaf(av,b1v.y,acc[r][5]); \
  acc[r][6]=fmaf(av,b1v.z,acc[r][6]); acc[r][7]=fmaf(av,b1v.w,acc[r][7]);

__global__ __launch_bounds__(256,3) void econv_gemm_kernel(
    const int* __restrict__ csrc, const int* __restrict__ enid,
    const float* __restrict__ P, const float* __restrict__ Q,
    const float* __restrict__ b1, const float* __restrict__ w2,
    unsigned int* __restrict__ enc){
  __shared__ __align__(16) float As[32*256];   // 32 KB (per k-half); lmax overlays after GEMM
  __shared__ __align__(16) float Ws[64*64];    // 16 KB
  __shared__ int eids[256];
  int tid = threadIdx.x;
  int e0 = ((blockIdx.x & 7)*640 + (blockIdx.x >> 3))*256;   // XCD-chunked (5120 wg)
  int e = e0 + tid;
  int j = csrc[e];
  int i = enid[e];
  eids[tid] = i;
  const float* Pr = P + (size_t)i*Hd;
  const float* Qr = Q + (size_t)j*Hd;
  #pragma unroll
  for (int c=0;c<16;c++) Ws[c*256 + tid] = w2[c*256 + tid];

  int m0 = tid >> 3, n0 = tid & 7;
  float acc[8][8];
  #pragma unroll
  for (int a=0;a<8;a++)
    #pragma unroll
    for (int b=0;b<8;b++) acc[a][b]=0.f;

  #pragma unroll 1
  for (int kh=0; kh<2; kh++){
    __syncthreads();
    #pragma unroll
    for (int c=0;c<8;c++){
      int k = kh*32 + 4*c;
      float4 q4 = *(const float4*)(Qr + k);
      float4 pk = *(const float4*)(Pr + k);
      float4 b4 = *(const float4*)(b1 + k);
      As[(4*c+0)*256 + tid] = fmaxf(pk.x+q4.x+b4.x, 0.f);
      As[(4*c+1)*256 + tid] = fmaxf(pk.y+q4.y+b4.y, 0.f);
      As[(4*c+2)*256 + tid] = fmaxf(pk.z+q4.z+b4.z, 0.f);
      As[(4*c+3)*256 + tid] = fmaxf(pk.w+q4.w+b4.w, 0.f);
    }
    __syncthreads();
    #pragma unroll 4
    for (int kk=0; kk<32; kk++){
      int k = kh*32 + kk;
      float4 a0 = *(const float4*)&As[kk*256 + 8*m0];
      float4 a1 = *(const float4*)&As[kk*256 + 8*m0 + 4];
      float4 b0 = *(const float4*)&Ws[k*64 + 8*n0];
      float4 b1v = *(const float4*)&Ws[k*64 + 8*n0 + 4];
      FMA8(a0.x, 0) FMA8(a0.y, 1) FMA8(a0.z, 2) FMA8(a0.w, 3)
      FMA8(a1.x, 4) FMA8(a1.y, 5) FMA8(a1.z, 6) FMA8(a1.w, 7)
    }
  }
  // ---- epilogue: per-block LDS max table, 1 global atomic/(node,ch)
  unsigned* lmax = (unsigned*)As;        // [32][65]
  int nfirst = eids[0];
  __syncthreads();
  for (int z = tid; z < 32*65; z += 256) lmax[z] = 0u;
  __syncthreads();
  {
    int rbase = 8*m0;
    int cur = eids[rbase];
    float vmax[8];
    #pragma unroll
    for (int b=0;b<8;b++) vmax[b] = -INFINITY;
    #pragma unroll
    for (int a=0;a<8;a++){
      int id = eids[rbase + a];
      if (id != cur){
        int lid = cur - nfirst;
        if (lid < 32){
          #pragma unroll
          for (int b=0;b<8;b++) atomicMax(&lmax[lid*65 + 8*n0 + b], enc_f32(vmax[b]));
        } else {
          #pragma unroll
          for (int b=0;b<8;b++) atomicMax(&enc[(size_t)cur*Hd + 8*n0 + b], enc_f32(vmax[b]));
        }
        #pragma unroll
        for (int b=0;b<8;b++) vmax[b] = -INFINITY;
        cur = id;
      }
      #pragma unroll
      for (int b=0;b<8;b++) vmax[b] = fmaxf(vmax[b], acc[a][b]);
    }
    int lid = cur - nfirst;
    if (lid < 32){
      #pragma unroll
      for (int b=0;b<8;b++) atomicMax(&lmax[lid*65 + 8*n0 + b], enc_f32(vmax[b]));
    } else {
      #pragma unroll
      for (int b=0;b<8;b++) atomicMax(&enc[(size_t)cur*Hd + 8*n0 + b], enc_f32(vmax[b]));
    }
  }
  __syncthreads();
  {
    int ch = tid & 63;
    for (int lid = tid >> 6; lid < 32; lid += 4){
      unsigned v = lmax[lid*65 + ch];
      if (v) atomicMax(&enc[(size_t)(nfirst + lid)*Hd + ch], v);
    }
  }
}

// ---------- kNN: bf16-MFMA approx distances + per-quarter top-24 (u32 keys)
// v5: 32-row tiles -> 2048 blocks, LDS 19712 B, parity-split scan lanes
// v6/v7: launch_bounds. (256,8)->budget 64: VGPR=32+AGPR split, kb[] spilled
//   (WRITE 231MB). (256,6)->budget 80: VGPR=40+AGPR copies, occ 47%, slow.
//   (256,4)->budget 128: expect clean ~64 arch VGPR (v4 precedent), residency
//   then LDS/VGPR-limited at ~7 blocks/CU (launch_bounds min is a floor, not cap).
__device__ __forceinline__ void ins24(unsigned (&kb)[KK], unsigned key){
  #pragma unroll
  for (int p=KK-1; p>0; p--){
    unsigned ins = (key < kb[p]) ? key : kb[p];
    kb[p] = (key < kb[p-1]) ? kb[p-1] : ins;
  }
  kb[0] = (key < kb[0]) ? key : kb[0];
}

#define KNN_FLUSH() do { \
  _Pragma("unroll 1") \
  for (int c=0;c<CAPB;c++){ \
    if (!__any(c < cnt)) break; \
    unsigned kf = (c < cnt) ? kc[c][tid] : 0xFFFFFFFFu; \
    ins24(kb, kf); \
  } \
  cnt = 0; kbLast = kb[KK-1]; \
} while(0)

#define KNN_TRY(key) do { unsigned kk_ = (key); \
  if (kk_ < kbLast){ kc[cnt][tid] = kk_; cnt++; } } while(0)

// swizzled LDS address: row-major [*][stride bytes], byte ^= (row&7)<<4
#define SWZ16(base, row, stridep2, byteoff) \
  ((unsigned short*)((char*)(base) + ((((row) << (stridep2)) + (byteoff)) ^ (((row) & 7) << 4))))

__global__ __launch_bounds__(256,4) void knn_kernel(
    const unsigned short* __restrict__ xb, const float* __restrict__ sq,
    unsigned short* __restrict__ cand){
  __shared__ __align__(16) char smem[19712];
  unsigned short* xjb = (unsigned short*)smem;            // [64 j][128B] swizzled, 8192
  unsigned short* Dt  = (unsigned short*)(smem + 8192);   // [32 r][128B] u16 keys swizzled, 4096
  unsigned (*kc)[256] = (unsigned(*)[256])(smem + 12288); // 7168
  float* sqs = (float*)(smem + 19456);                    // 64 f32 = 256
  unsigned* mgb = (unsigned*)smem;                        // overlay after loop: [128][24] u32

  int tid = threadIdx.x;
  int lane = tid & 63, w = tid >> 6;
  int bid = ((blockIdx.x & 7) << 8) | (blockIdx.x >> 3);  // XCD-chunked (2048 wg)
  int g  = bid >> 6;
  int r0 = (bid & 63) * 32;
  const unsigned short* xbg = xb + (size_t)g*Ng*Hd;
  const float* sg = sq + (size_t)g*Ng;

  int r = tid & 31;           // scan row (0..31)
  int q = (tid >> 5) & 3;     // quarter (512 cols each)
  int h = tid >> 7;           // iteration-parity half (wave-uniform)
  int mrow = (w & 1) * 16;    // MFMA row base for this wave
  int cbase = (w >> 1) * 32;  // MFMA local col base for this wave

  // ---- A fragments direct from global (rows are L2-hot; no LDS staging)
  bf16x8 A0 = *(const bf16x8*)(xbg + (size_t)(r0 + mrow + (lane & 15))*Hd + (lane>>4)*8);
  bf16x8 A1 = *(const bf16x8*)(xbg + (size_t)(r0 + mrow + (lane & 15))*Hd + 32 + (lane>>4)*8);

  // ---- stage first 64-col tile (4 quarters x 16 cols) + sqs
  {
    int jr = tid >> 2, seg = tid & 3;
    int jloc = (jr >> 4)*512 + (jr & 15);
    const uint4* src = (const uint4*)(xbg + (size_t)jloc*Hd + seg*16);
    uint4 a = src[0], b = src[1];
    *(uint4*)SWZ16(xjb, jr, 7, seg*32)      = a;
    *(uint4*)SWZ16(xjb, jr, 7, seg*32 + 16) = b;
    if (tid < 64) sqs[tid] = sg[(tid>>4)*512 + (tid & 15)];
  }

  unsigned kb[KK];
  #pragma unroll
  for (int t=0;t<KK;t++) kb[t] = 0xFFFFFFFFu;
  unsigned kbLast = 0xFFFFFFFFu;
  int cnt = 0;

  __syncthreads();

  #pragma unroll 1
  for (int it = 0; it < 32; it++){
    uint4 pf0, pf1; float psq = 0.f;
    int itn = it + 1;
    int jr = tid >> 2, seg = tid & 3;
    if (itn < 32){
      int jloc = (jr >> 4)*512 + itn*16 + (jr & 15);
      const uint4* src = (const uint4*)(xbg + (size_t)jloc*Hd + seg*16);
      pf0 = src[0]; pf1 = src[1];
      if (tid < 64) psq = sg[(tid>>4)*512 + itn*16 + (tid & 15)];
    }
    // MFMA: wave w computes rows mrow..mrow+15 x local cols cbase..cbase+31
    #pragma unroll
    for (int jb = 0; jb < 2; jb++){
      int cl = cbase + jb*16 + (lane & 15);
      bf16x8 B0 = *(const bf16x8*)SWZ16(xjb, cl, 7,      (lane>>4)*16);
      bf16x8 B1 = *(const bf16x8*)SWZ16(xjb, cl, 7, 64 + (lane>>4)*16);
      f32x4 acc = {0.f, 0.f, 0.f, 0.f};
      acc = __builtin_amdgcn_mfma_f32_16x16x32_bf16(A0, B0, acc, 0, 0, 0);
      acc = __builtin_amdgcn_mfma_f32_16x16x32_bf16(A1, B1, acc, 0, 0, 0);
      float sqv = sqs[cl];
      int rbase = mrow + (lane>>4)*4;
      #pragma unroll
      for (int v=0; v<4; v++){
        float f = fmaf(acc[v], -2.f, sqv);
        unsigned u = __float_as_uint(f);
        unsigned t2 = ((unsigned)((int)u >> 31)) | 0x8000u;
        *SWZ16(Dt, rbase + v, 7, cl*2) = (unsigned short)((u >> 16) ^ t2);
      }
    }
    __syncthreads();
    // scan: only parity-matching half (wave-uniform branch)
    if ((it & 1) == h){
      int cb0 = q*512 + it*16;
      const char* dbase = (const char*)Dt + (r << 7);
      unsigned m = (r & 7) << 4;
      uint4 dv0 = *(const uint4*)(dbase + ((unsigned)(q*32) ^ m));
      uint4 dv1 = *(const uint4*)(dbase + ((unsigned)(q*32 + 16) ^ m));
      #pragma unroll
      for (int r4=0; r4<2; r4++){
        uint4 dv = r4 ? dv1 : dv0;
        int cb = cb0 + r4*8;
        KNN_TRY((dv.x << 16) + (unsigned)(cb + 0));
        KNN_TRY((dv.x & 0xFFFF0000u) | (unsigned)(cb + 1));
        KNN_TRY((dv.y << 16) + (unsigned)(cb + 2));
        KNN_TRY((dv.y & 0xFFFF0000u) | (unsigned)(cb + 3));
        if (__any(cnt >= 4)) KNN_FLUSH();
        KNN_TRY((dv.z << 16) + (unsigned)(cb + 4));
        KNN_TRY((dv.z & 0xFFFF0000u) | (unsigned)(cb + 5));
        KNN_TRY((dv.w << 16) + (unsigned)(cb + 6));
        KNN_TRY((dv.w & 0xFFFF0000u) | (unsigned)(cb + 7));
        if (__any(cnt >= 4)) KNN_FLUSH();
      }
    }
    if (itn < 32){
      *(uint4*)SWZ16(xjb, jr, 7, seg*32)      = pf0;
      *(uint4*)SWZ16(xjb, jr, 7, seg*32 + 16) = pf1;
      if (tid < 64) sqs[tid] = psq;
    }
    __syncthreads();
  }
  KNN_FLUSH();

  // ---- pairwise exact merge: (r,q,h=0) + (r,q,h=1) sorted 24-lists -> top-24
  __syncthreads();             // xjb/Dt dead; mgb overlays
  int sl = tid & 127;
  if (h == 1){
    #pragma unroll
    for (int t=0;t<KK;t++) mgb[sl*24 + t] = kb[t];
  }
  __syncthreads();
  if (h == 0){
    size_t base = (size_t)(g*Ng + r0 + r)*96 + q*24;
    int j = 0;
    unsigned bv = mgb[sl*24];
    #pragma unroll
    for (int i=0;i<KK;i++){
      unsigned av = kb[i];
      #pragma unroll 1
      while (j < KK && bv < av){
        int rk = i + j;
        if (rk < KK) cand[base + rk] = (unsigned short)(bv & 2047u);
        j++;
        bv = (j < KK) ? mgb[sl*24 + j] : 0xFFFFFFFFu;
      }
      int rk = i + j;
      if (rk < KK) cand[base + rk] = (unsigned short)(av & 2047u);
    }
  }
}

// ---------- exact rerank v4: XCD-chunked blocks + preloaded cand idx + unroll-2 gather pipeline
#define RR_REDUCE(BB, HH) do { \
  int c = (2*pp + HH)*16 + cg; \
  int j = js[2*pp + HH]; \
  float dot = 0.f, sqj = 0.f; \
  _Pragma("unroll") \
  for (int it2=0; it2<4; it2++){ \
    float4 b = BB[it2]; \
    float4 a = xc[it2]; \
    dot = fmaf(a.x, b.x, dot); dot = fmaf(a.y, b.y, dot); \
    dot = fmaf(a.z, b.z, dot); dot = fmaf(a.w, b.w, dot); \
    sqj = fmaf(b.x, b.x, sqj); sqj = fmaf(b.y, b.y, sqj); \
    sqj = fmaf(b.z, b.z, sqj); sqj = fmaf(b.w, b.w, sqj); \
  } \
  dot += __shfl_xor(dot, 1, 64); dot += __shfl_xor(dot, 2, 64); \
  sqj += __shfl_xor(sqj, 1, 64); sqj += __shfl_xor(sqj, 2, 64); \
  if (chunk == 0){ \
    float dist = fmaf(dot, -2.f, sqj); \
    ks[w][c] = ((unsigned long long)enc_f32(dist) << 32) | (unsigned)j; \
  } \
} while(0)

__global__ __launch_bounds__(256) void rerank_kernel(const float* __restrict__ x,
        const unsigned short* __restrict__ cand, int* __restrict__ idx){
  __shared__ __align__(16) unsigned long long ks[4][96];
  int tid = threadIdx.x;
  int lane = tid & 63, w = tid >> 6;
  int bid = ((blockIdx.x & 7) << 11) | (blockIdx.x >> 3);   // XCD-chunked (16384 wg)
  int row = bid*4 + w;
  int g = row >> 11;
  const float* xg = x + (size_t)g*Ng*Hd;
  int chunk = lane & 3;        // 16B chunk within a row
  int cg = lane >> 2;          // candidate group 0..15
  // xrow chunks this lane needs: floats [16*it + 4*chunk .. +3]
  const float* xr = x + (size_t)row*Hd;
  float4 xc[4];
  #pragma unroll
  for (int it2=0; it2<4; it2++) xc[it2] = *(const float4*)(xr + 16*it2 + 4*chunk);

  int js[6];
  #pragma unroll
  for (int p=0; p<6; p++) js[p] = cand[(size_t)row*96 + p*16 + cg];

  #pragma unroll 1
  for (int pp=0; pp<3; pp++){
    const float* xj0 = xg + (size_t)js[2*pp]*Hd;
    const float* xj1 = xg + (size_t)js[2*pp+1]*Hd;
    float4 bb0[4], bb1[4];
    #pragma unroll
    for (int it2=0; it2<4; it2++){
      bb0[it2] = *(const float4*)(xj0 + 16*it2 + 4*chunk);
      bb1[it2] = *(const float4*)(xj1 + 16*it2 + 4*chunk);
    }
    RR_REDUCE(bb0, 0);
    RR_REDUCE(bb1, 1);
  }
  __syncthreads();
  unsigned long long k0 = ks[w][lane];
  unsigned long long k1 = (lane < 32) ? ks[w][64 + lane] : ~0ULL;
  int r0 = 0, r1 = 0;
  #pragma unroll
  for (int c=0;c<96;c+=2){
    unsigned long long a = ks[w][c], b = ks[w][c+1];
    r0 += (a < k0) + (b < k0);
    r1 += (a < k1) + (b < k1);
  }
  if (r0 < Kn) idx[(size_t)row*Kn + r0] = g*Ng + (int)(k0 & 2047ULL);
  if (lane < 32 && r1 < Kn) idx[(size_t)row*Kn + r1] = g*Ng + (int)(k1 & 2047ULL);
}

// ---------- dynamic EdgeConv stage 2: edge-batched GEMM + node-max + atomicMax(enc)
__global__ __launch_bounds__(256,3) void emsg_kernel(
    const int* __restrict__ srcl,
    const float* __restrict__ P, const float* __restrict__ Q,
    const float* __restrict__ b1, const float* __restrict__ w2,
    unsigned int* __restrict__ enc){
  __shared__ __align__(16) char smem[49152];
  float* As = (float*)smem;
  float* Ws = (float*)(smem + 32768);
  float* p0 = (float*)smem;
  float* p1 = (float*)(smem + 64*33*4);
  int tid = threadIdx.x;
  int e0 = ((blockIdx.x & 7)*640 + (blockIdx.x >> 3))*256;   // XCD-chunked (5120 wg)
  int e = e0 + tid;
  int i = e / Kn;
  int j = srcl[e];
  const float* Pr = P + (size_t)i*Hd;
  const float* Qr = Q + (size_t)j*Hd;
  #pragma unroll
  for (int c=0;c<16;c++) Ws[c*256 + tid] = w2[c*256 + tid];

  int m0 = tid >> 3, n0 = tid & 7;
  float acc[8][8];
  #pragma unroll
  for (int a=0;a<8;a++)
    #pragma unroll
    for (int b=0;b<8;b++) acc[a][b]=0.f;

  #pragma unroll 1
  for (int kh=0; kh<2; kh++){
    __syncthreads();
    #pragma unroll
    for (int c=0;c<8;c++){
      int k = kh*32 + 4*c;
      float4 q4 = *(const float4*)(Qr + k);
      float4 pk = *(const float4*)(Pr + k);
      float4 b4 = *(const float4*)(b1 + k);
      As[(4*c+0)*256 + tid] = fmaxf(pk.x+q4.x+b4.x, 0.f);
      As[(4*c+1)*256 + tid] = fmaxf(pk.y+q4.y+b4.y, 0.f);
      As[(4*c+2)*256 + tid] = fmaxf(pk.z+q4.z+b4.z, 0.f);
      As[(4*c+3)*256 + tid] = fmaxf(pk.w+q4.w+b4.w, 0.f);
    }
    __syncthreads();
    #pragma unroll 4
    for (int kk=0; kk<32; kk++){
      int k = kh*32 + kk;
      float4 a0 = *(const float4*)&As[kk*256 + 8*m0];
      float4 a1 = *(const float4*)&As[kk*256 + 8*m0 + 4];
      float4 b0 = *(const float4*)&Ws[k*64 + 8*n0];
      float4 b1v = *(const float4*)&Ws[k*64 + 8*n0 + 4];
      FMA8(a0.x, 0) FMA8(a0.y, 1) FMA8(a0.z, 2) FMA8(a0.w, 3)
      FMA8(a1.x, 4) FMA8(a1.y, 5) FMA8(a1.z, 6) FMA8(a1.w, 7)
    }
  }
  int ebase = e0 + 8*m0;
  int nd0 = ebase / Kn;
  int split = (nd0+1)*Kn - ebase; if (split > 8) split = 8;
  float s0[8], s1[8];
  #pragma unroll
  for (int b=0;b<8;b++){ s0[b] = -INFINITY; s1[b] = -INFINITY; }
  #pragma unroll
  for (int a=0;a<8;a++)
    #pragma unroll
    for (int b=0;b<8;b++){
      if (a < split) s0[b] = fmaxf(s0[b], acc[a][b]);
      else           s1[b] = fmaxf(s1[b], acc[a][b]);
    }
  __syncthreads();
  #pragma unroll
  for (int b=0;b<8;b++){
    p0[(8*n0+b)*33 + m0] = s0[b];
    p1[(8*n0+b)*33 + m0] = s1[b];
  }
  __syncthreads();
  int nfirst = e0 / Kn;
  int ncnt = (e0 + 255) / Kn - nfirst + 1;
  int ch = tid & 63;
  for (int ln = tid >> 6; ln < ncnt; ln += 4){
    int nd = nfirst + ln;
    int glo = nd*Kn;      if (glo < e0)     glo = e0;
    int ghi = nd*Kn + Kn; if (ghi > e0+256) ghi = e0+256;
    int mlo = (glo - e0) >> 3, mhi = (ghi - 1 - e0) >> 3;
    float v = -INFINITY;
    for (int mm = mlo; mm <= mhi; mm++){
      int bn = (e0 + 8*mm) / Kn;
      if (bn == nd)     v = fmaxf(v, p0[ch*33 + mm]);
      if (bn + 1 == nd) v = fmaxf(v, p1[ch*33 + mm]);
    }
    atomicMax(&enc[(size_t)nd*Hd + ch], enc_f32(v));
  }
}

// ---------- final decode (no ELU): enc -> float + b2
__global__ __launch_bounds__(256) void decode_kernel(const unsigned int* __restrict__ enc,
         const float* __restrict__ b2, float* __restrict__ x){
  int t = blockIdx.x*256 + threadIdx.x;
  unsigned int e = enc[t];
  unsigned int bits = (e & 0x80000000u) ? (e ^ 0x80000000u) : ~e;
  float f = __uint_as_float(bits);
  if (isfinite(f)) f += b2[t & 63]; else f = 0.f;
  x[t] = f;
}

__global__ __launch_bounds__(64) void final_kernel(const float* __restrict__ h,
        const float* __restrict__ w, const float* __restrict__ bias,
        float* __restrict__ out){
  __shared__ float xs[Hd];
  int c = threadIdx.x;
  float wc[Hd];
  float bc = 0.f;
  if (c < Cd){
    #pragma unroll
    for (int d=0; d<Hd; d++) wc[d] = w[d*Cd + c];
    bc = bias[c];
  }
  for (int i = blockIdx.x; i < BNn; i += gridDim.x){
    __syncthreads();
    xs[c] = h[(size_t)i*Hd + c];
    __syncthreads();
    if (c < Cd){
      float s = bc;
      #pragma unroll
      for (int d=0; d<Hd; d++) s = fmaf(xs[d], wc[d], s);
      out[(size_t)i*Cd + c] = s;
    }
  }
}

extern "C" void kernel_launch(void* const* d_in, const int* in_sizes, int n_in,
                              void* d_out, int out_size, void* d_ws, size_t ws_size,
                              hipStream_t stream){
  const float* x0   = (const float*)d_in[0];
  const int*   ei   = (const int*)d_in[1];
  const float* c1w1 = (const float*)d_in[3];
  const float* c1b1 = (const float*)d_in[4];
  const float* c1w2 = (const float*)d_in[5];
  const float* c1b2 = (const float*)d_in[6];
  const float* d1w1 = (const float*)d_in[7];
  const float* d1b1 = (const float*)d_in[8];
  const float* d1w2 = (const float*)d_in[9];
  const float* d1b2 = (const float*)d_in[10];
  const float* d2w1 = (const float*)d_in[11];
  const float* d2b1 = (const float*)d_in[12];
  const float* d2w2 = (const float*)d_in[13];
  const float* d2b2 = (const float*)d_in[14];
  const float* linw = (const float*)d_in[15];
  const float* linb = (const float*)d_in[16];
  float* out = (float*)d_out;

  char* ws = (char*)d_ws;
  size_t off = 0;
  auto alloc = [&](size_t bytes)->char*{
    char* p = ws + off; off += (bytes + 255) & ~(size_t)255; return p;
  };
  float*        X    = (float*)alloc(sizeof(float)*(size_t)BNn*Hd);
  float*        P    = (float*)alloc(sizeof(float)*(size_t)BNn*Hd);
  float*        Q    = (float*)alloc(sizeof(float)*(size_t)BNn*Hd);
  float*        H2   = (float*)alloc(sizeof(float)*(size_t)BNn*Hd);  // aliases XB, ENID
  unsigned int* ENC  = (unsigned int*)alloc(sizeof(unsigned)*(size_t)BNn*Hd); // aliases CAND
  int*          SHRD = (int*)alloc(sizeof(int)*(size_t)En);   // CSRC, later IDX
  int*          DEG  = (int*)alloc(sizeof(int)*BNn);
  int*          RPTR = (int*)alloc(sizeof(int)*(BNn+1));
  int*          CUR  = (int*)alloc(sizeof(int)*BNn);
  float*        SQ   = (float*)alloc(sizeof(float)*BNn);
  float*        WPQ0 = (float*)alloc(sizeof(float)*3*128);
  float*        WPQ1 = (float*)alloc(sizeof(float)*64*128);
  float*        WPQ2 = (float*)alloc(sizeof(float)*64*128);
  int*            CSRC = SHRD;
  int*            IDX  = SHRD;
  int*            ENID = (int*)H2;
  unsigned short* XB   = (unsigned short*)H2;
  unsigned short* CAND = (unsigned short*)ENC;
  (void)ws_size; (void)in_sizes; (void)n_in; (void)out_size;

  // static EdgeConv: CSR sort + edge-batched GEMM + LDS-reduced max + fused decode
  prep_w_kernel<<<32, 256, 0, stream>>>(c1w1, d1w1, d2w1, WPQ0, WPQ1, WPQ2);
  zero_kernel<<<BNn/256, 256, 0, stream>>>(DEG);
  count_kernel<<<En/256, 256, 0, stream>>>(ei, DEG);
  gemm_pq_kernel<3><<<BNn/8, 128, 0, stream>>>(x0, WPQ0, P, Q);
  scan_kernel<<<1, 1024, 0, stream>>>(DEG, RPTR, CUR);
  scatter_kernel<<<En/256, 256, 0, stream>>>(ei, CUR, CSRC, ENID);
  init_enc_kernel<<<BNn*Hd/256, 256, 0, stream>>>(ENC);
  econv_gemm_kernel<<<En/256, 256, 0, stream>>>(CSRC, ENID, P, Q, c1b1, c1w2, ENC);
  decode_sqxb_kernel<<<BNn*Hd/256, 256, 0, stream>>>(ENC, c1b2, X, SQ, XB);

  // dynamic layer 1
  gemm_pq_kernel<64><<<BNn/8, 128, 0, stream>>>(X, WPQ1, P, Q);
  knn_kernel<<<Bg*64, 256, 0, stream>>>(XB, SQ, CAND);
  rerank_kernel<<<BNn/4, 256, 0, stream>>>(X, CAND, IDX);
  init_enc_kernel<<<BNn*Hd/256, 256, 0, stream>>>(ENC);
  emsg_kernel<<<En/256, 256, 0, stream>>>(IDX, P, Q, d1b1, d1w2, ENC);
  decode_sqxb_kernel<<<BNn*Hd/256, 256, 0, stream>>>(ENC, d1b2, X, SQ, XB);

  // dynamic layer 2
  gemm_pq_kernel<64><<<BNn/8, 128, 0, stream>>>(X, WPQ2, P, Q);
  knn_kernel<<<Bg*64, 256, 0, stream>>>(XB, SQ, CAND);
  rerank_kernel<<<BNn/4, 256, 0, stream>>>(X, CAND, IDX);
  init_enc_kernel<<<BNn*Hd/256, 256, 0, stream>>>(ENC);
  emsg_kernel<<<En/256, 256, 0, stream>>>(IDX, P, Q, d2b1, d2w2, ENC);
  decode_kernel<<<BNn*Hd/256, 256, 0, stream>>>(ENC, d2b2, H2);

  final_kernel<<<8192, 64, 0, stream>>>(H2, linw, linb, out);
}

// Round 7
// 1425.313 us; speedup vs baseline: 1.2593x; 1.2593x over previous
//
#include <hip/hip_runtime.h>
#include <math.h>

#define Bg 32
#define Ng 2048
#define Kn 20
#define BNn (Bg*Ng)
#define En (BNn*Kn)
#define Hd 64
#define Cd 40

// knn-mfma params
#define KK 24            // approx top-K kept per j-quarter (96 cands/row)
#define CAPB 7

typedef __attribute__((ext_vector_type(8))) short bf16x8;
typedef __attribute__((ext_vector_type(4))) float f32x4;

__device__ __forceinline__ unsigned enc_f32(float f){
  unsigned u = __float_as_uint(f);
  return ((int)u < 0) ? ~u : (u | 0x80000000u);
}

// ---------- weight prep
__global__ void prep_w_kernel(const float* __restrict__ w1c, const float* __restrict__ w1d1,
                              const float* __restrict__ w1d2,
                              float* __restrict__ wpq0, float* __restrict__ wpq1,
                              float* __restrict__ wpq2){
  int t = blockIdx.x*256 + threadIdx.x;
  if (t < 3*128){
    int d = t >> 7, l = t & 127;
    wpq0[t] = (l < 64) ? (w1c[d*64 + l] - w1c[(d+3)*64 + l]) : w1c[(d+3)*64 + (l-64)];
  }
  if (t < 64*128){
    int d = t >> 7, l = t & 127;
    wpq1[t] = (l < 64) ? (w1d1[d*64 + l] - w1d1[(d+64)*64 + l]) : w1d1[(d+64)*64 + (l-64)];
    wpq2[t] = (l < 64) ? (w1d2[d*64 + l] - w1d2[(d+64)*64 + l]) : w1d2[(d+64)*64 + (l-64)];
  }
}

__global__ void zero_kernel(int* __restrict__ p){
  p[blockIdx.x*256 + threadIdx.x] = 0;
}

__global__ void init_enc_kernel(unsigned int* __restrict__ enc){
  enc[blockIdx.x*256 + threadIdx.x] = 0x007FFFFFu;   // enc(-inf)
}

// ---------- X[BN,D] @ wpq[D,128] -> P,Q
template<int D>
__global__ __launch_bounds__(128) void gemm_pq_kernel(const float* __restrict__ x,
                               const float* __restrict__ w,
                               float* __restrict__ P, float* __restrict__ Q){
  __shared__ float xs[8*D];
  int l = threadIdx.x;
  int node0 = blockIdx.x*8;
  float wc[D];
  #pragma unroll
  for (int d=0; d<D; d++) wc[d] = w[d*128 + l];
  for (int i=l; i < 8*D; i += 128) xs[i] = x[(size_t)node0*D + i];
  __syncthreads();
  #pragma unroll
  for (int n=0; n<8; n++){
    float s = 0.f;
    #pragma unroll
    for (int d=0; d<D; d++) s = fmaf(xs[n*D+d], wc[d], s);
    int node = node0 + n;
    if (l < 64) P[(size_t)node*64 + l] = s;
    else        Q[(size_t)node*64 + (l-64)] = s;
  }
}

// ---------- sq norms + bf16 copy of X (first static layer input path)
__global__ __launch_bounds__(256) void sqxb_kernel(const float* __restrict__ x,
        float* __restrict__ sq, unsigned short* __restrict__ xb){
  int t = blockIdx.x*256 + threadIdx.x;
  int node = t >> 6, l = t & 63;
  float v = x[t];
  unsigned u = __float_as_uint(v);
  xb[t] = (unsigned short)((u + 0x7FFFu + ((u >> 16) & 1u)) >> 16);  // RNE fp32->bf16
  float s = v*v;
  #pragma unroll
  for (int o=32; o; o>>=1) s += __shfl_xor(s, o, 64);
  if (l == 0) sq[node] = s;
}

// ---------- fused decode(+b2,+ELU) -> X, bf16 XB, SQ
__global__ __launch_bounds__(256) void decode_sqxb_kernel(const unsigned int* __restrict__ enc,
        const float* __restrict__ b2, float* __restrict__ x,
        float* __restrict__ sq, unsigned short* __restrict__ xb){
  int t = blockIdx.x*256 + threadIdx.x;
  int node = t >> 6, l = t & 63;
  unsigned int e = enc[t];
  unsigned int bits = (e & 0x80000000u) ? (e ^ 0x80000000u) : ~e;
  float f = __uint_as_float(bits);
  if (isfinite(f)) f += b2[l]; else f = 0.f;
  f = f > 0.f ? f : expm1f(f);
  x[t] = f;
  unsigned u = __float_as_uint(f);
  xb[t] = (unsigned short)((u + 0x7FFFu + ((u >> 16) & 1u)) >> 16);
  float s = f*f;
  #pragma unroll
  for (int o=32; o; o>>=1) s += __shfl_xor(s, o, 64);
  if (l == 0) sq[node] = s;
}

// ---------- CSR build
__global__ void count_kernel(const int* __restrict__ ei, int* __restrict__ deg){
  int e = blockIdx.x*256 + threadIdx.x;
  atomicAdd(&deg[ei[En + e]], 1);
}

__global__ __launch_bounds__(1024) void scan_kernel(const int* __restrict__ deg,
        int* __restrict__ rowptr, int* __restrict__ cursor){
  __shared__ int ps[1024];
  int t = threadIdx.x;
  int base = t*64;
  int s = 0;
  for (int k=0;k<64;k++) s += deg[base+k];
  ps[t] = s; __syncthreads();
  for (int off=1; off<1024; off<<=1){
    int v = (t>=off) ? ps[t-off] : 0;
    __syncthreads();
    ps[t] += v;
    __syncthreads();
  }
  int run = (t>0) ? ps[t-1] : 0;
  for (int k=0;k<64;k++){
    rowptr[base+k] = run; cursor[base+k] = run;
    run += deg[base+k];
  }
  if (t==1023) rowptr[BNn] = run;
}

__global__ void scatter_kernel(const int* __restrict__ ei, int* __restrict__ cursor,
                               int* __restrict__ csrc, int* __restrict__ enid){
  int e = blockIdx.x*256 + threadIdx.x;
  int s = ei[e], d = ei[En + e];
  int pos = atomicAdd(&cursor[d], 1);
  csrc[pos] = s;
  enid[pos] = d;
}

// ---------- static EdgeConv as edge-batched GEMM + LDS-reduced node-max epilogue
#define FMA8(av, r) \
  acc[r][0]=fmaf(av,b0.x,acc[r][0]); acc[r][1]=fmaf(av,b0.y,acc[r][1]); \
  acc[r][2]=fmaf(av,b0.z,acc[r][2]); acc[r][3]=fmaf(av,b0.w,acc[r][3]); \
  acc[r][4]=fmaf(av,b1v.x,acc[r][4]); acc[r][5]=fmaf(av,b1v.y,acc[r][5]); \
  acc[r][6]=fmaf(av,b1v.z,acc[r][6]); acc[r][7]=fmaf(av,b1v.w,acc[r][7]);

__global__ __launch_bounds__(256,3) void econv_gemm_kernel(
    const int* __restrict__ csrc, const int* __restrict__ enid,
    const float* __restrict__ P, const float* __restrict__ Q,
    const float* __restrict__ b1, const float* __restrict__ w2,
    unsigned int* __restrict__ enc){
  __shared__ __align__(16) float As[32*256];   // 32 KB (per k-half); lmax overlays after GEMM
  __shared__ __align__(16) float Ws[64*64];    // 16 KB
  __shared__ int eids[256];
  int tid = threadIdx.x;
  int e0 = ((blockIdx.x & 7)*640 + (blockIdx.x >> 3))*256;   // XCD-chunked (5120 wg)
  int e = e0 + tid;
  int j = csrc[e];
  int i = enid[e];
  eids[tid] = i;
  const float* Pr = P + (size_t)i*Hd;
  const float* Qr = Q + (size_t)j*Hd;
  #pragma unroll
  for (int c=0;c<16;c++) Ws[c*256 + tid] = w2[c*256 + tid];

  int m0 = tid >> 3, n0 = tid & 7;
  float acc[8][8];
  #pragma unroll
  for (int a=0;a<8;a++)
    #pragma unroll
    for (int b=0;b<8;b++) acc[a][b]=0.f;

  #pragma unroll 1
  for (int kh=0; kh<2; kh++){
    __syncthreads();
    #pragma unroll
    for (int c=0;c<8;c++){
      int k = kh*32 + 4*c;
      float4 q4 = *(const float4*)(Qr + k);
      float4 pk = *(const float4*)(Pr + k);
      float4 b4 = *(const float4*)(b1 + k);
      As[(4*c+0)*256 + tid] = fmaxf(pk.x+q4.x+b4.x, 0.f);
      As[(4*c+1)*256 + tid] = fmaxf(pk.y+q4.y+b4.y, 0.f);
      As[(4*c+2)*256 + tid] = fmaxf(pk.z+q4.z+b4.z, 0.f);
      As[(4*c+3)*256 + tid] = fmaxf(pk.w+q4.w+b4.w, 0.f);
    }
    __syncthreads();
    #pragma unroll 4
    for (int kk=0; kk<32; kk++){
      int k = kh*32 + kk;
      float4 a0 = *(const float4*)&As[kk*256 + 8*m0];
      float4 a1 = *(const float4*)&As[kk*256 + 8*m0 + 4];
      float4 b0 = *(const float4*)&Ws[k*64 + 8*n0];
      float4 b1v = *(const float4*)&Ws[k*64 + 8*n0 + 4];
      FMA8(a0.x, 0) FMA8(a0.y, 1) FMA8(a0.z, 2) FMA8(a0.w, 3)
      FMA8(a1.x, 4) FMA8(a1.y, 5) FMA8(a1.z, 6) FMA8(a1.w, 7)
    }
  }
  // ---- epilogue: per-block LDS max table, 1 global atomic/(node,ch)
  unsigned* lmax = (unsigned*)As;        // [32][65]
  int nfirst = eids[0];
  __syncthreads();
  for (int z = tid; z < 32*65; z += 256) lmax[z] = 0u;
  __syncthreads();
  {
    int rbase = 8*m0;
    int cur = eids[rbase];
    float vmax[8];
    #pragma unroll
    for (int b=0;b<8;b++) vmax[b] = -INFINITY;
    #pragma unroll
    for (int a=0;a<8;a++){
      int id = eids[rbase + a];
      if (id != cur){
        int lid = cur - nfirst;
        if (lid < 32){
          #pragma unroll
          for (int b=0;b<8;b++) atomicMax(&lmax[lid*65 + 8*n0 + b], enc_f32(vmax[b]));
        } else {
          #pragma unroll
          for (int b=0;b<8;b++) atomicMax(&enc[(size_t)cur*Hd + 8*n0 + b], enc_f32(vmax[b]));
        }
        #pragma unroll
        for (int b=0;b<8;b++) vmax[b] = -INFINITY;
        cur = id;
      }
      #pragma unroll
      for (int b=0;b<8;b++) vmax[b] = fmaxf(vmax[b], acc[a][b]);
    }
    int lid = cur - nfirst;
    if (lid < 32){
      #pragma unroll
      for (int b=0;b<8;b++) atomicMax(&lmax[lid*65 + 8*n0 + b], enc_f32(vmax[b]));
    } else {
      #pragma unroll
      for (int b=0;b<8;b++) atomicMax(&enc[(size_t)cur*Hd + 8*n0 + b], enc_f32(vmax[b]));
    }
  }
  __syncthreads();
  {
    int ch = tid & 63;
    for (int lid = tid >> 6; lid < 32; lid += 4){
      unsigned v = lmax[lid*65 + ch];
      if (v) atomicMax(&enc[(size_t)(nfirst + lid)*Hd + ch], v);
    }
  }
}

// ---------- kNN: bf16-MFMA approx distances + per-quarter top-24 (u32 keys)
// v8 = R3's proven v4 (64-row tiles, 1024 wg, 16 iters) with ONE change:
//   A-fragments load direct from global (L2-hot rows, proven in v5) -> xrb
//   staging buffer removed; kc/sqs get dedicated LDS. Total 40448 B (was
//   40960 exact-fit, which resulted in only 3 blocks/CU in R3).
//   [v5 32-row restructure abandoned: 3 rounds (R4-R6), allocator produced
//    32/40/52 VGPR pathologies at every launch_bounds setting, never beat v4.]
__device__ __forceinline__ void ins24(unsigned (&kb)[KK], unsigned key){
  #pragma unroll
  for (int p=KK-1; p>0; p--){
    unsigned ins = (key < kb[p]) ? key : kb[p];
    kb[p] = (key < kb[p-1]) ? kb[p-1] : ins;
  }
  kb[0] = (key < kb[0]) ? key : kb[0];
}

#define KNN_FLUSH() do { \
  _Pragma("unroll 1") \
  for (int c=0;c<CAPB;c++){ \
    if (!__any(c < cnt)) break; \
    unsigned kf = (c < cnt) ? kc[c][tid] : 0xFFFFFFFFu; \
    ins24(kb, kf); \
  } \
  cnt = 0; kbLast = kb[KK-1]; \
} while(0)

#define KNN_TRY(key) do { unsigned kk_ = (key); \
  if (kk_ < kbLast){ kc[cnt][tid] = kk_; cnt++; } } while(0)

// swizzled LDS address: row-major [*][stride bytes], byte ^= (row&7)<<4
#define SWZ16(base, row, stridep2, byteoff) \
  ((unsigned short*)((char*)(base) + ((((row) << (stridep2)) + (byteoff)) ^ (((row) & 7) << 4))))

__global__ __launch_bounds__(256,4) void knn_kernel(
    const unsigned short* __restrict__ xb, const float* __restrict__ sq,
    unsigned short* __restrict__ cand){
  __shared__ __align__(16) unsigned short xjb[128*64];    // 16384 B (swizzled)
  __shared__ __align__(16) unsigned short Dt[64*128];     // 16384 B (u16 keys, swizzled)
  __shared__ unsigned kc[CAPB][256];                      // 7168 B
  __shared__ float sqs[128];                              // 512 B  => 40448 B total

  int tid = threadIdx.x;
  int lane = tid & 63, w = tid >> 6;
  int bid = ((blockIdx.x & 7) << 7) | (blockIdx.x >> 3);  // XCD-chunked (1024 wg)
  int g  = bid >> 5;
  int r0 = (bid & 31) * 64;
  const unsigned short* xbg = xb + (size_t)g*Ng*Hd;
  const float* sg = sq + (size_t)g*Ng;

  int q = w;
  int prow = lane;
  int rw = w*16;

  // ---- A fragments direct from global (rows are L2-hot; no LDS staging)
  bf16x8 A0, A1;
  {
    int arow = r0 + rw + (lane & 15);
    A0 = *(const bf16x8*)(xbg + (size_t)arow*Hd +      (lane>>4)*8);
    A1 = *(const bf16x8*)(xbg + (size_t)arow*Hd + 32 + (lane>>4)*8);
  }
  // ---- stage xjb (swizzled) + sqs
  {
    int jr = tid >> 1, half = tid & 1;
    int jloc = (jr >> 5)*512 + (jr & 31);
    const uint4* src = (const uint4*)(xbg + (size_t)jloc*Hd + half*32);
    uint4 a = src[0], b = src[1], c2 = src[2], d2 = src[3];
    *(uint4*)SWZ16(xjb, jr, 7, half*64 +  0) = a;
    *(uint4*)SWZ16(xjb, jr, 7, half*64 + 16) = b;
    *(uint4*)SWZ16(xjb, jr, 7, half*64 + 32) = c2;
    *(uint4*)SWZ16(xjb, jr, 7, half*64 + 48) = d2;
    if (tid < 128) sqs[tid] = sg[(tid>>5)*512 + (tid&31)];
  }

  unsigned kb[KK];
  #pragma unroll
  for (int t=0;t<KK;t++) kb[t] = 0xFFFFFFFFu;
  unsigned kbLast = 0xFFFFFFFFu;
  int cnt = 0;

  __syncthreads();

  #pragma unroll 1
  for (int it = 0; it < 16; it++){
    uint4 pf0, pf1, pf2, pf3; float psq = 0.f;
    int itn = it + 1;
    int jr = tid >> 1, half = tid & 1;
    if (itn < 16){
      int jloc = (jr >> 5)*512 + itn*32 + (jr & 31);
      const uint4* src = (const uint4*)(xbg + (size_t)jloc*Hd + half*32);
      pf0 = src[0]; pf1 = src[1]; pf2 = src[2]; pf3 = src[3];
      if (tid < 128) psq = sg[(tid>>5)*512 + itn*32 + (tid&31)];
    }
    #pragma unroll
    for (int jb = 0; jb < 8; jb++){
      int brow = jb*16 + (lane & 15);
      bf16x8 B0 = *(const bf16x8*)SWZ16(xjb, brow, 7,      (lane>>4)*16);
      bf16x8 B1 = *(const bf16x8*)SWZ16(xjb, brow, 7, 64 + (lane>>4)*16);
      f32x4 acc = {0.f, 0.f, 0.f, 0.f};
      acc = __builtin_amdgcn_mfma_f32_16x16x32_bf16(A0, B0, acc, 0, 0, 0);
      acc = __builtin_amdgcn_mfma_f32_16x16x32_bf16(A1, B1, acc, 0, 0, 0);
      int col = jb*16 + (lane & 15);
      float sqv = sqs[col];
      int rbase = rw + (lane>>4)*4;
      #pragma unroll
      for (int v=0; v<4; v++){
        // sortable u16 encode of f = -2*dot + sqj  (top 16 bits of sign-flipped f32)
        float f = fmaf(acc[v], -2.f, sqv);
        unsigned u = __float_as_uint(f);
        unsigned t2 = ((unsigned)((int)u >> 31)) | 0x8000u;
        *SWZ16(Dt, rbase + v, 8, col*2) = (unsigned short)((u >> 16) ^ t2);
      }
    }
    __syncthreads();
    int jbase0 = q*512 + it*32;
    {
      const char* dbase = (const char*)Dt + (prow << 8);
      unsigned m = (prow & 7) << 4;
      #pragma unroll
      for (int r4=0; r4<4; r4++){
        uint4 dv = *(const uint4*)(dbase + ((unsigned)(q*64 + r4*16) ^ m));
        int cb = jbase0 + r4*8;
        KNN_TRY((dv.x << 16) + (unsigned)(cb + 0));
        KNN_TRY((dv.x & 0xFFFF0000u) | (unsigned)(cb + 1));
        KNN_TRY((dv.y << 16) + (unsigned)(cb + 2));
        KNN_TRY((dv.y & 0xFFFF0000u) | (unsigned)(cb + 3));
        if (__any(cnt >= 4)) KNN_FLUSH();
        KNN_TRY((dv.z << 16) + (unsigned)(cb + 4));
        KNN_TRY((dv.z & 0xFFFF0000u) | (unsigned)(cb + 5));
        KNN_TRY((dv.w << 16) + (unsigned)(cb + 6));
        KNN_TRY((dv.w & 0xFFFF0000u) | (unsigned)(cb + 7));
        if (__any(cnt >= 4)) KNN_FLUSH();
      }
    }
    if (itn < 16){
      *(uint4*)SWZ16(xjb, jr, 7, half*64 +  0) = pf0;
      *(uint4*)SWZ16(xjb, jr, 7, half*64 + 16) = pf1;
      *(uint4*)SWZ16(xjb, jr, 7, half*64 + 32) = pf2;
      *(uint4*)SWZ16(xjb, jr, 7, half*64 + 48) = pf3;
      if (tid < 128) sqs[tid] = psq;
    }
    __syncthreads();
  }
  KNN_FLUSH();
  size_t base = (size_t)(g*Ng + r0 + prow)*96 + q*24;
  #pragma unroll
  for (int t=0;t<KK;t++)
    cand[base + t] = (unsigned short)(kb[t] & 2047u);
}

// ---------- exact rerank v5: XCD-chunked + all-24-loads-in-flight gather pipeline
__global__ __launch_bounds__(256,2) void rerank_kernel(const float* __restrict__ x,
        const unsigned short* __restrict__ cand, int* __restrict__ idx){
  __shared__ __align__(16) unsigned long long ks[4][96];
  int tid = threadIdx.x;
  int lane = tid & 63, w = tid >> 6;
  int bid = ((blockIdx.x & 7) << 11) | (blockIdx.x >> 3);   // XCD-chunked (16384 wg)
  int row = bid*4 + w;
  int g = row >> 11;
  const float* xg = x + (size_t)g*Ng*Hd;
  int chunk = lane & 3;        // 16B chunk within a row
  int cg = lane >> 2;          // candidate group 0..15
  const float* xr = x + (size_t)row*Hd;
  float4 xc[4];
  #pragma unroll
  for (int it2=0; it2<4; it2++) xc[it2] = *(const float4*)(xr + 16*it2 + 4*chunk);

  int js[6];
  #pragma unroll
  for (int p=0; p<6; p++) js[p] = cand[(size_t)row*96 + p*16 + cg];

  // phase 1: issue all 24 gathers (static indices -> registers, deep MLP)
  float4 bb[6][4];
  #pragma unroll
  for (int p=0; p<6; p++){
    const float* xj = xg + (size_t)js[p]*Hd;
    #pragma unroll
    for (int it2=0; it2<4; it2++) bb[p][it2] = *(const float4*)(xj + 16*it2 + 4*chunk);
  }
  // phase 2: reduce
  #pragma unroll
  for (int p=0; p<6; p++){
    float dot = 0.f, sqj = 0.f;
    #pragma unroll
    for (int it2=0; it2<4; it2++){
      float4 b = bb[p][it2];
      float4 a = xc[it2];
      dot = fmaf(a.x, b.x, dot); dot = fmaf(a.y, b.y, dot);
      dot = fmaf(a.z, b.z, dot); dot = fmaf(a.w, b.w, dot);
      sqj = fmaf(b.x, b.x, sqj); sqj = fmaf(b.y, b.y, sqj);
      sqj = fmaf(b.z, b.z, sqj); sqj = fmaf(b.w, b.w, sqj);
    }
    dot += __shfl_xor(dot, 1, 64); dot += __shfl_xor(dot, 2, 64);
    sqj += __shfl_xor(sqj, 1, 64); sqj += __shfl_xor(sqj, 2, 64);
    if (chunk == 0){
      float dist = fmaf(dot, -2.f, sqj);   // row-constant +sq_i dropped (order-invariant)
      ks[w][p*16 + cg] = ((unsigned long long)enc_f32(dist) << 32) | (unsigned)js[p];
    }
  }
  __syncthreads();
  unsigned long long k0 = ks[w][lane];
  unsigned long long k1 = (lane < 32) ? ks[w][64 + lane] : ~0ULL;
  int r0 = 0, r1 = 0;
  #pragma unroll
  for (int c=0;c<96;c+=2){
    unsigned long long a = ks[w][c], b = ks[w][c+1];
    r0 += (a < k0) + (b < k0);
    r1 += (a < k1) + (b < k1);
  }
  if (r0 < Kn) idx[(size_t)row*Kn + r0] = g*Ng + (int)(k0 & 2047ULL);
  if (lane < 32 && r1 < Kn) idx[(size_t)row*Kn + r1] = g*Ng + (int)(k1 & 2047ULL);
}

// ---------- dynamic EdgeConv stage 2: edge-batched GEMM + node-max + atomicMax(enc)
__global__ __launch_bounds__(256,3) void emsg_kernel(
    const int* __restrict__ srcl,
    const float* __restrict__ P, const float* __restrict__ Q,
    const float* __restrict__ b1, const float* __restrict__ w2,
    unsigned int* __restrict__ enc){
  __shared__ __align__(16) char smem[49152];
  float* As = (float*)smem;
  float* Ws = (float*)(smem + 32768);
  float* p0 = (float*)smem;
  float* p1 = (float*)(smem + 64*33*4);
  int tid = threadIdx.x;
  int e0 = ((blockIdx.x & 7)*640 + (blockIdx.x >> 3))*256;   // XCD-chunked (5120 wg)
  int e = e0 + tid;
  int i = e / Kn;
  int j = srcl[e];
  const float* Pr = P + (size_t)i*Hd;
  const float* Qr = Q + (size_t)j*Hd;
  #pragma unroll
  for (int c=0;c<16;c++) Ws[c*256 + tid] = w2[c*256 + tid];

  int m0 = tid >> 3, n0 = tid & 7;
  float acc[8][8];
  #pragma unroll
  for (int a=0;a<8;a++)
    #pragma unroll
    for (int b=0;b<8;b++) acc[a][b]=0.f;

  #pragma unroll 1
  for (int kh=0; kh<2; kh++){
    __syncthreads();
    #pragma unroll
    for (int c=0;c<8;c++){
      int k = kh*32 + 4*c;
      float4 q4 = *(const float4*)(Qr + k);
      float4 pk = *(const float4*)(Pr + k);
      float4 b4 = *(const float4*)(b1 + k);
      As[(4*c+0)*256 + tid] = fmaxf(pk.x+q4.x+b4.x, 0.f);
      As[(4*c+1)*256 + tid] = fmaxf(pk.y+q4.y+b4.y, 0.f);
      As[(4*c+2)*256 + tid] = fmaxf(pk.z+q4.z+b4.z, 0.f);
      As[(4*c+3)*256 + tid] = fmaxf(pk.w+q4.w+b4.w, 0.f);
    }
    __syncthreads();
    #pragma unroll 4
    for (int kk=0; kk<32; kk++){
      int k = kh*32 + kk;
      float4 a0 = *(const float4*)&As[kk*256 + 8*m0];
      float4 a1 = *(const float4*)&As[kk*256 + 8*m0 + 4];
      float4 b0 = *(const float4*)&Ws[k*64 + 8*n0];
      float4 b1v = *(const float4*)&Ws[k*64 + 8*n0 + 4];
      FMA8(a0.x, 0) FMA8(a0.y, 1) FMA8(a0.z, 2) FMA8(a0.w, 3)
      FMA8(a1.x, 4) FMA8(a1.y, 5) FMA8(a1.z, 6) FMA8(a1.w, 7)
    }
  }
  int ebase = e0 + 8*m0;
  int nd0 = ebase / Kn;
  int split = (nd0+1)*Kn - ebase; if (split > 8) split = 8;
  float s0[8], s1[8];
  #pragma unroll
  for (int b=0;b<8;b++){ s0[b] = -INFINITY; s1[b] = -INFINITY; }
  #pragma unroll
  for (int a=0;a<8;a++)
    #pragma unroll
    for (int b=0;b<8;b++){
      if (a < split) s0[b] = fmaxf(s0[b], acc[a][b]);
      else           s1[b] = fmaxf(s1[b], acc[a][b]);
    }
  __syncthreads();
  #pragma unroll
  for (int b=0;b<8;b++){
    p0[(8*n0+b)*33 + m0] = s0[b];
    p1[(8*n0+b)*33 + m0] = s1[b];
  }
  __syncthreads();
  int nfirst = e0 / Kn;
  int ncnt = (e0 + 255) / Kn - nfirst + 1;
  int ch = tid & 63;
  for (int ln = tid >> 6; ln < ncnt; ln += 4){
    int nd = nfirst + ln;
    int glo = nd*Kn;      if (glo < e0)     glo = e0;
    int ghi = nd*Kn + Kn; if (ghi > e0+256) ghi = e0+256;
    int mlo = (glo - e0) >> 3, mhi = (ghi - 1 - e0) >> 3;
    float v = -INFINITY;
    for (int mm = mlo; mm <= mhi; mm++){
      int bn = (e0 + 8*mm) / Kn;
      if (bn == nd)     v = fmaxf(v, p0[ch*33 + mm]);
      if (bn + 1 == nd) v = fmaxf(v, p1[ch*33 + mm]);
    }
    atomicMax(&enc[(size_t)nd*Hd + ch], enc_f32(v));
  }
}

// ---------- final decode (no ELU): enc -> float + b2
__global__ __launch_bounds__(256) void decode_kernel(const unsigned int* __restrict__ enc,
         const float* __restrict__ b2, float* __restrict__ x){
  int t = blockIdx.x*256 + threadIdx.x;
  unsigned int e = enc[t];
  unsigned int bits = (e & 0x80000000u) ? (e ^ 0x80000000u) : ~e;
  float f = __uint_as_float(bits);
  if (isfinite(f)) f += b2[t & 63]; else f = 0.f;
  x[t] = f;
}

__global__ __launch_bounds__(64) void final_kernel(const float* __restrict__ h,
        const float* __restrict__ w, const float* __restrict__ bias,
        float* __restrict__ out){
  __shared__ float xs[Hd];
  int c = threadIdx.x;
  float wc[Hd];
  float bc = 0.f;
  if (c < Cd){
    #pragma unroll
    for (int d=0; d<Hd; d++) wc[d] = w[d*Cd + c];
    bc = bias[c];
  }
  for (int i = blockIdx.x; i < BNn; i += gridDim.x){
    __syncthreads();
    xs[c] = h[(size_t)i*Hd + c];
    __syncthreads();
    if (c < Cd){
      float s = bc;
      #pragma unroll
      for (int d=0; d<Hd; d++) s = fmaf(xs[d], wc[d], s);
      out[(size_t)i*Cd + c] = s;
    }
  }
}

extern "C" void kernel_launch(void* const* d_in, const int* in_sizes, int n_in,
                              void* d_out, int out_size, void* d_ws, size_t ws_size,
                              hipStream_t stream){
  const float* x0   = (const float*)d_in[0];
  const int*   ei   = (const int*)d_in[1];
  const float* c1w1 = (const float*)d_in[3];
  const float* c1b1 = (const float*)d_in[4];
  const float* c1w2 = (const float*)d_in[5];
  const float* c1b2 = (const float*)d_in[6];
  const float* d1w1 = (const float*)d_in[7];
  const float* d1b1 = (const float*)d_in[8];
  const float* d1w2 = (const float*)d_in[9];
  const float* d1b2 = (const float*)d_in[10];
  const float* d2w1 = (const float*)d_in[11];
  const float* d2b1 = (const float*)d_in[12];
  const float* d2w2 = (const float*)d_in[13];
  const float* d2b2 = (const float*)d_in[14];
  const float* linw = (const float*)d_in[15];
  const float* linb = (const float*)d_in[16];
  float* out = (float*)d_out;

  char* ws = (char*)d_ws;
  size_t off = 0;
  auto alloc = [&](size_t bytes)->char*{
    char* p = ws + off; off += (bytes + 255) & ~(size_t)255; return p;
  };
  float*        X    = (float*)alloc(sizeof(float)*(size_t)BNn*Hd);
  float*        P    = (float*)alloc(sizeof(float)*(size_t)BNn*Hd);
  float*        Q    = (float*)alloc(sizeof(float)*(size_t)BNn*Hd);
  float*        H2   = (float*)alloc(sizeof(float)*(size_t)BNn*Hd);  // aliases XB, ENID
  unsigned int* ENC  = (unsigned int*)alloc(sizeof(unsigned)*(size_t)BNn*Hd); // aliases CAND
  int*          SHRD = (int*)alloc(sizeof(int)*(size_t)En);   // CSRC, later IDX
  int*          DEG  = (int*)alloc(sizeof(int)*BNn);
  int*          RPTR = (int*)alloc(sizeof(int)*(BNn+1));
  int*          CUR  = (int*)alloc(sizeof(int)*BNn);
  float*        SQ   = (float*)alloc(sizeof(float)*BNn);
  float*        WPQ0 = (float*)alloc(sizeof(float)*3*128);
  float*        WPQ1 = (float*)alloc(sizeof(float)*64*128);
  float*        WPQ2 = (float*)alloc(sizeof(float)*64*128);
  int*            CSRC = SHRD;
  int*            IDX  = SHRD;
  int*            ENID = (int*)H2;
  unsigned short* XB   = (unsigned short*)H2;
  unsigned short* CAND = (unsigned short*)ENC;
  (void)ws_size; (void)in_sizes; (void)n_in; (void)out_size;

  // static EdgeConv: CSR sort + edge-batched GEMM + LDS-reduced max + fused decode
  prep_w_kernel<<<32, 256, 0, stream>>>(c1w1, d1w1, d2w1, WPQ0, WPQ1, WPQ2);
  zero_kernel<<<BNn/256, 256, 0, stream>>>(DEG);
  count_kernel<<<En/256, 256, 0, stream>>>(ei, DEG);
  gemm_pq_kernel<3><<<BNn/8, 128, 0, stream>>>(x0, WPQ0, P, Q);
  scan_kernel<<<1, 1024, 0, stream>>>(DEG, RPTR, CUR);
  scatter_kernel<<<En/256, 256, 0, stream>>>(ei, CUR, CSRC, ENID);
  init_enc_kernel<<<BNn*Hd/256, 256, 0, stream>>>(ENC);
  econv_gemm_kernel<<<En/256, 256, 0, stream>>>(CSRC, ENID, P, Q, c1b1, c1w2, ENC);
  decode_sqxb_kernel<<<BNn*Hd/256, 256, 0, stream>>>(ENC, c1b2, X, SQ, XB);

  // dynamic layer 1
  gemm_pq_kernel<64><<<BNn/8, 128, 0, stream>>>(X, WPQ1, P, Q);
  knn_kernel<<<Bg*32, 256, 0, stream>>>(XB, SQ, CAND);
  rerank_kernel<<<BNn/4, 256, 0, stream>>>(X, CAND, IDX);
  init_enc_kernel<<<BNn*Hd/256, 256, 0, stream>>>(ENC);
  emsg_kernel<<<En/256, 256, 0, stream>>>(IDX, P, Q, d1b1, d1w2, ENC);
  decode_sqxb_kernel<<<BNn*Hd/256, 256, 0, stream>>>(ENC, d1b2, X, SQ, XB);

  // dynamic layer 2
  gemm_pq_kernel<64><<<BNn/8, 128, 0, stream>>>(X, WPQ2, P, Q);
  knn_kernel<<<Bg*32, 256, 0, stream>>>(XB, SQ, CAND);
  rerank_kernel<<<BNn/4, 256, 0, stream>>>(X, CAND, IDX);
  init_enc_kernel<<<BNn*Hd/256, 256, 0, stream>>>(ENC);
  emsg_kernel<<<En/256, 256, 0, stream>>>(IDX, P, Q, d2b1, d2w2, ENC);
  decode_kernel<<<BNn*Hd/256, 256, 0, stream>>>(ENC, d2b2, H2);

  final_kernel<<<8192, 64, 0, stream>>>(H2, linw, linb, out);
}